// Round 9
// baseline (7676.699 us; speedup 1.0000x reference)
//
#include <hip/hip_runtime.h>
#include <hip/hip_bf16.h>
#include <stdint.h>

#define T_STEPS 12
#define NN 20000
#define NE 320000
#define FIN 128
#define HD 256
#define FOUT 128

typedef __attribute__((ext_vector_type(4))) float f32x4;
typedef __attribute__((ext_vector_type(8))) _Float16 f16x8;

static __device__ __forceinline__ float sigmoidf_(float x) {
  return 1.0f / (1.0f + __expf(-x));
}
static __device__ __forceinline__ ushort f2h(float f) {
  union { ushort s; _Float16 h; } v; v.h = (_Float16)f; return v.s;
}

// ---------------- CSR build ----------------
__global__ void count_kernel(const int* __restrict__ dst, int* __restrict__ counts) {
  int e = blockIdx.x * blockDim.x + threadIdx.x;
  if (e < NE) atomicAdd(&counts[dst[e]], 1);
}

__global__ void scan_kernel(const int* __restrict__ counts, int* __restrict__ offs,
                            int* __restrict__ cursor) {
  __shared__ int sm[1024];
  __shared__ int carry_s;
  if (threadIdx.x == 0) carry_s = 0;
  __syncthreads();
  const int n = NN;
  int nch = (n + 1023) >> 10;
  for (int c = 0; c < nch; ++c) {
    int i = (c << 10) + (int)threadIdx.x;
    int v = (i < n) ? counts[i] : 0;
    sm[threadIdx.x] = v;
    __syncthreads();
    for (int off = 1; off < 1024; off <<= 1) {
      int t = (threadIdx.x >= (unsigned)off) ? sm[threadIdx.x - off] : 0;
      __syncthreads();
      sm[threadIdx.x] += t;
      __syncthreads();
    }
    int incl = sm[threadIdx.x];
    int carry_local = carry_s;
    if (i < n) {
      int excl = carry_local + incl - v;
      offs[i] = excl;
      cursor[i] = excl;
    }
    __syncthreads();
    if (threadIdx.x == 1023) carry_s = carry_local + incl;
    __syncthreads();
  }
  if (threadIdx.x == 0) offs[n] = carry_s;
}

__global__ void fill_kernel(const int* __restrict__ src, const int* __restrict__ dst,
                            int* __restrict__ cursor, int* __restrict__ esrc) {
  int e = blockIdx.x * blockDim.x + threadIdx.x;
  if (e < NE) {
    int d = dst[e];
    int pos = atomicAdd(&cursor[d], 1);
    esrc[pos] = src[e];
  }
}

// ---------------- aggregation: fp32 gather-sum -> fp16 hi/lo split output ----------------
// out row (stride ld): hi at [0..W), lo at [W..2W). 4-way unrolled edge loop.
template <int W>
__global__ void agg_split(const float* __restrict__ feat, const int* __restrict__ offs,
                          const int* __restrict__ esrc, _Float16* __restrict__ out, int ld) {
  constexpr int PL = W / 64;  // floats per lane (2 or 4)
  int d = blockIdx.x * 4 + (threadIdx.x >> 6);
  int lane = threadIdx.x & 63;
  int beg = offs[d], end = offs[d + 1];
  float a0[PL] = {}, a1[PL] = {}, a2[PL] = {}, a3[PL] = {};
  int e = beg;
  for (; e + 3 < end; e += 4) {
    const float* r0 = feat + (size_t)esrc[e] * W + lane * PL;
    const float* r1 = feat + (size_t)esrc[e + 1] * W + lane * PL;
    const float* r2 = feat + (size_t)esrc[e + 2] * W + lane * PL;
    const float* r3 = feat + (size_t)esrc[e + 3] * W + lane * PL;
    if constexpr (PL == 2) {
      float2 v0 = *reinterpret_cast<const float2*>(r0);
      float2 v1 = *reinterpret_cast<const float2*>(r1);
      float2 v2 = *reinterpret_cast<const float2*>(r2);
      float2 v3 = *reinterpret_cast<const float2*>(r3);
      a0[0] += v0.x; a0[1] += v0.y; a1[0] += v1.x; a1[1] += v1.y;
      a2[0] += v2.x; a2[1] += v2.y; a3[0] += v3.x; a3[1] += v3.y;
    } else {
      float4 v0 = *reinterpret_cast<const float4*>(r0);
      float4 v1 = *reinterpret_cast<const float4*>(r1);
      float4 v2 = *reinterpret_cast<const float4*>(r2);
      float4 v3 = *reinterpret_cast<const float4*>(r3);
      a0[0] += v0.x; a0[1] += v0.y; a0[2] += v0.z; a0[3] += v0.w;
      a1[0] += v1.x; a1[1] += v1.y; a1[2] += v1.z; a1[3] += v1.w;
      a2[0] += v2.x; a2[1] += v2.y; a2[2] += v2.z; a2[3] += v2.w;
      a3[0] += v3.x; a3[1] += v3.y; a3[2] += v3.z; a3[3] += v3.w;
    }
  }
  for (; e < end; ++e) {
    const float* r0 = feat + (size_t)esrc[e] * W + lane * PL;
    if constexpr (PL == 2) {
      float2 v0 = *reinterpret_cast<const float2*>(r0);
      a0[0] += v0.x; a0[1] += v0.y;
    } else {
      float4 v0 = *reinterpret_cast<const float4*>(r0);
      a0[0] += v0.x; a0[1] += v0.y; a0[2] += v0.z; a0[3] += v0.w;
    }
  }
  ushort hi[PL], lo[PL];
#pragma unroll
  for (int p = 0; p < PL; ++p) {
    float a = (a0[p] + a1[p]) + (a2[p] + a3[p]);
    hi[p] = f2h(a);
    union { ushort s; _Float16 h; } u; u.s = hi[p];
    lo[p] = f2h(a - (float)u.h);
  }
  if constexpr (PL == 2) {
    *reinterpret_cast<ushort2*>(out + (size_t)d * ld + lane * 2) = *reinterpret_cast<ushort2*>(hi);
    *reinterpret_cast<ushort2*>(out + (size_t)d * ld + W + lane * 2) = *reinterpret_cast<ushort2*>(lo);
  } else {
    *reinterpret_cast<ushort4*>(out + (size_t)d * ld + lane * 4) = *reinterpret_cast<ushort4*>(hi);
    *reinterpret_cast<ushort4*>(out + (size_t)d * ld + W + lane * 4) = *reinterpret_cast<ushort4*>(lo);
  }
}

// batched x-aggregation over all T steps: grid (NN/4, T); out [t][N][256] = [hi128|lo128]
__global__ void agg_split_x(const float* __restrict__ x, const int* __restrict__ offs,
                            const int* __restrict__ esrc, _Float16* __restrict__ out) {
  int t = blockIdx.y;
  const float* feat = x + (size_t)t * NN * FIN;
  _Float16* o = out + (size_t)t * NN * 256;
  int d = blockIdx.x * 4 + (threadIdx.x >> 6);
  int lane = threadIdx.x & 63;
  int beg = offs[d], end = offs[d + 1];
  float a0[2] = {}, a1[2] = {}, a2[2] = {}, a3[2] = {};
  int e = beg;
  for (; e + 3 < end; e += 4) {
    float2 v0 = *reinterpret_cast<const float2*>(feat + (size_t)esrc[e] * FIN + lane * 2);
    float2 v1 = *reinterpret_cast<const float2*>(feat + (size_t)esrc[e + 1] * FIN + lane * 2);
    float2 v2 = *reinterpret_cast<const float2*>(feat + (size_t)esrc[e + 2] * FIN + lane * 2);
    float2 v3 = *reinterpret_cast<const float2*>(feat + (size_t)esrc[e + 3] * FIN + lane * 2);
    a0[0] += v0.x; a0[1] += v0.y; a1[0] += v1.x; a1[1] += v1.y;
    a2[0] += v2.x; a2[1] += v2.y; a3[0] += v3.x; a3[1] += v3.y;
  }
  for (; e < end; ++e) {
    float2 v0 = *reinterpret_cast<const float2*>(feat + (size_t)esrc[e] * FIN + lane * 2);
    a0[0] += v0.x; a0[1] += v0.y;
  }
  float s0 = (a0[0] + a1[0]) + (a2[0] + a3[0]);
  float s1 = (a0[1] + a1[1]) + (a2[1] + a3[1]);
  ushort2 hi, lo;
  hi.x = f2h(s0); hi.y = f2h(s1);
  union { ushort s; _Float16 h; } u0, u1;
  u0.s = hi.x; u1.s = hi.y;
  lo.x = f2h(s0 - (float)u0.h); lo.y = f2h(s1 - (float)u1.h);
  *reinterpret_cast<ushort2*>(o + (size_t)d * 256 + lane * 2) = hi;
  *reinterpret_cast<ushort2*>(o + (size_t)d * 256 + FIN + lane * 2) = lo;
}

// ---------------- fp16 MFMA GEMM: two A-sources with per-source K-wrap ----------------
// Logical A col k: k < lenA -> Aa col (k>=wrapA ? k-wrapA : k); else Ab col with wrapB.
// (K-wrap re-reads the hi segment for the wlo weight term: 3-term split GEMM.)
// mode 0: C = acc+bias. mode 1 (fused GRU r/u): cols<256 -> rh=sigmoid(v)*h;
// 256..511 -> xw=sigmoid(v); >=512 -> xw=v. mode 2 (fused GRU c, nch=2):
// nh = u*h + (1-u)*tanh(xw_c + acc); writes h (+fp16 mirror hf).
// XCD-local flat grid: xcd=p&7 owns a contiguous row-tile band.
__global__ __launch_bounds__(256) void gemm_f16(
    const _Float16* __restrict__ Aa, int lda_a, int wrapA, int lenA,
    const _Float16* __restrict__ Ab, int lda_b, int wrapB,
    const _Float16* __restrict__ B, int ldb,
    float* __restrict__ C, int ldc, const float* __restrict__ bias,
    int M, int K, int mode, float* __restrict__ h, _Float16* __restrict__ hf,
    float* __restrict__ rh, int nch, int rpg) {
  __shared__ _Float16 As[128 * 64];
  __shared__ _Float16 Bs[128 * 64];

  int p = blockIdx.x;
  int xcd = p & 7;
  int q = p >> 3;
  int rowt = xcd * rpg + q / nch;
  int chunk = q % nch;
  int m0 = rowt * 128;
  if (m0 >= M) return;
  int n0 = chunk * 128;

  int tid = threadIdx.x;
  int wave = tid >> 6;
  int lane = tid & 63;
  int wm = wave >> 1, wn = wave & 1;
  int lrow = lane & 15;
  int kgrp = lane >> 4;

  f32x4 acc[4][4] = {};

  int srow = tid >> 3;       // 0..31
  int skb = (tid & 7) * 16;  // staged byte col

  uint4 av[4], bv[4];
  auto load_tile = [&](int k0) {
    const _Float16* Abase;
    int ka, ldA;
    if (k0 < lenA) {
      ka = (k0 >= wrapA) ? k0 - wrapA : k0;
      Abase = Aa; ldA = lda_a;
    } else {
      int kp = k0 - lenA;
      ka = (kp >= wrapB) ? kp - wrapB : kp;
      Abase = Ab; ldA = lda_b;
    }
#pragma unroll
    for (int p4 = 0; p4 < 4; ++p4) {
      int row = p4 * 32 + srow;
      int gr = m0 + row;
      av[p4] = (gr < M)
                   ? *reinterpret_cast<const uint4*>(&Abase[(size_t)gr * ldA + ka + (tid & 7) * 8])
                   : make_uint4(0, 0, 0, 0);
      bv[p4] = *reinterpret_cast<const uint4*>(&B[(size_t)(n0 + row) * ldb + k0 + (tid & 7) * 8]);
    }
  };

  load_tile(0);
  for (int k0 = 0; k0 < K; k0 += 64) {
    __syncthreads();  // previous iteration's ds_reads done before overwrite
#pragma unroll
    for (int p4 = 0; p4 < 4; ++p4) {
      int row = p4 * 32 + srow;
      int off = row * 128 + (skb ^ ((row & 7) << 4));
      *reinterpret_cast<uint4*>(reinterpret_cast<char*>(As) + off) = av[p4];
      *reinterpret_cast<uint4*>(reinterpret_cast<char*>(Bs) + off) = bv[p4];
    }
    __syncthreads();
    if (k0 + 64 < K) load_tile(k0 + 64);  // prefetch in flight under MFMA

#pragma unroll
    for (int kk = 0; kk < 2; ++kk) {
      f16x8 af[4], bf[4];
      int kbyte = kk * 64 + kgrp * 16;
#pragma unroll
      for (int i = 0; i < 4; ++i) {
        int ar = wm * 64 + i * 16 + lrow;
        af[i] = *reinterpret_cast<const f16x8*>(
            reinterpret_cast<const char*>(As) + ar * 128 + (kbyte ^ ((ar & 7) << 4)));
        int br = wn * 64 + i * 16 + lrow;
        bf[i] = *reinterpret_cast<const f16x8*>(
            reinterpret_cast<const char*>(Bs) + br * 128 + (kbyte ^ ((br & 7) << 4)));
      }
      // operand-swapped: lane's 4 acc regs = 4 consecutive output COLUMNS
#pragma unroll
      for (int i = 0; i < 4; ++i)
#pragma unroll
        for (int j = 0; j < 4; ++j)
          acc[i][j] = __builtin_amdgcn_mfma_f32_16x16x32_f16(bf[j], af[i], acc[i][j], 0, 0, 0);
    }
  }

  // epilogue: acc[i][j][r] -> row m0+wm*64+i*16+lrow, col n0+wn*64+j*16+kgrp*4+r
#pragma unroll
  for (int i = 0; i < 4; ++i) {
    int m = m0 + wm * 64 + i * 16 + lrow;
    if (m >= M) continue;
#pragma unroll
    for (int j = 0; j < 4; ++j) {
      int colbase = n0 + wn * 64 + j * 16 + kgrp * 4;
      f32x4 v = acc[i][j];
      if (mode == 0) {
        float4 bv4 = *reinterpret_cast<const float4*>(&bias[colbase]);
        v[0] += bv4.x; v[1] += bv4.y; v[2] += bv4.z; v[3] += bv4.w;
        *reinterpret_cast<f32x4*>(&C[(size_t)m * ldc + colbase]) = v;
      } else if (mode == 1) {
        float4 bv4 = *reinterpret_cast<const float4*>(&bias[colbase]);
        v[0] += bv4.x; v[1] += bv4.y; v[2] += bv4.z; v[3] += bv4.w;
        if (colbase < 256) {  // r-gate: rh = sigmoid(r)*h
          float4 hv = *reinterpret_cast<const float4*>(&h[(size_t)m * 256 + colbase]);
          f32x4 rv;
          rv[0] = sigmoidf_(v[0]) * hv.x;
          rv[1] = sigmoidf_(v[1]) * hv.y;
          rv[2] = sigmoidf_(v[2]) * hv.z;
          rv[3] = sigmoidf_(v[3]) * hv.w;
          *reinterpret_cast<f32x4*>(&rh[(size_t)m * 256 + colbase]) = rv;
        } else if (colbase < 512) {  // u-gate: store sigmoid(u)
          v[0] = sigmoidf_(v[0]); v[1] = sigmoidf_(v[1]);
          v[2] = sigmoidf_(v[2]); v[3] = sigmoidf_(v[3]);
          *reinterpret_cast<f32x4*>(&C[(size_t)m * ldc + colbase]) = v;
        } else {  // c x-part preact
          *reinterpret_cast<f32x4*>(&C[(size_t)m * ldc + colbase]) = v;
        }
      } else {  // mode 2: fused c-gate + GRU state update (colbase in [0,256))
        float4 xc = *reinterpret_cast<const float4*>(&C[(size_t)m * ldc + 512 + colbase]);
        float4 uu = *reinterpret_cast<const float4*>(&C[(size_t)m * ldc + 256 + colbase]);
        float* hp = &h[(size_t)m * 256 + colbase];
        float4 hv = *reinterpret_cast<const float4*>(hp);
        float4 nh;
        nh.x = uu.x * hv.x + (1.f - uu.x) * tanhf(xc.x + v[0]);
        nh.y = uu.y * hv.y + (1.f - uu.y) * tanhf(xc.y + v[1]);
        nh.z = uu.z * hv.z + (1.f - uu.z) * tanhf(xc.z + v[2]);
        nh.w = uu.w * hv.w + (1.f - uu.w) * tanhf(xc.w + v[3]);
        *reinterpret_cast<float4*>(hp) = nh;
        if (hf) {
          ushort4 hv16;
          hv16.x = f2h(nh.x); hv16.y = f2h(nh.y);
          hv16.z = f2h(nh.z); hv16.w = f2h(nh.w);
          *reinterpret_cast<ushort4*>(&hf[(size_t)m * 256 + colbase]) = hv16;
        }
      }
    }
  }
}

// ---------------- weight prep ----------------
// mode 0: dst[n][koff+k] = fp16(W[k*ldw+n]); mode 1: fp16 residual (W - fp16(W))
__global__ void wtrans(const float* __restrict__ W, _Float16* __restrict__ dst,
                       int K, int ldw, int ldd, int koff, int mode) {
  int k = blockIdx.x * blockDim.x + threadIdx.x;
  int n = blockIdx.y;
  if (k < K) {
    float w = W[(size_t)k * ldw + n];
    _Float16 hi = (_Float16)w;
    dst[(size_t)n * ldd + koff + k] = mode ? (_Float16)(w - (float)hi) : hi;
  }
}

__global__ void bias_comb(const float* __restrict__ bx, const float* __restrict__ bh,
                          float* __restrict__ out) {
  int i = blockIdx.x * blockDim.x + threadIdx.x;
  if (i < 768) out[i] = bx[i] + bh[i];
}

__global__ void copy_kernel(const float* __restrict__ in, float* __restrict__ out, int n4) {
  int i = blockIdx.x * blockDim.x + threadIdx.x;
  if (i < n4) reinterpret_cast<float4*>(out)[i] = reinterpret_cast<const float4*>(in)[i];
}

// ---------------- host ----------------
extern "C" void kernel_launch(void* const* d_in, const int* in_sizes, int n_in,
                              void* d_out, int out_size, void* d_ws, size_t ws_size,
                              hipStream_t stream) {
  const float* x   = (const float*)d_in[0];
  const float* h0  = (const float*)d_in[1];
  const int*   src = (const int*)d_in[2];
  const int*   dst = (const int*)d_in[3];
  const float* Wx0 = (const float*)d_in[4];
  const float* bx0 = (const float*)d_in[5];
  const float* Wh0 = (const float*)d_in[6];
  const float* bh0 = (const float*)d_in[7];
  const float* Wx1 = (const float*)d_in[8];
  const float* bx1 = (const float*)d_in[9];
  const float* Wh1 = (const float*)d_in[10];
  const float* bh1 = (const float*)d_in[11];
  const float* Wo  = (const float*)d_in[12];
  const float* bo  = (const float*)d_in[13];
  float* out = (float*)d_out;

  char* p = (char*)d_ws;
  auto alloc = [&](size_t bytes) {
    char* r = p;
    p += (bytes + 255) & ~(size_t)255;
    return r;
  };
  int* offs   = (int*)alloc((NN + 1) * sizeof(int));
  int* cursor = (int*)alloc(NN * sizeof(int));
  int* counts = (int*)alloc(NN * sizeof(int));
  int* esrc   = (int*)alloc(NE * sizeof(int));
  // B panels [N][K] fp16, 3-term K layout per source: [Whi | Whi | Wlo]
  _Float16* B0  = (_Float16*)alloc((size_t)768 * 1152 * 2);  // x:384 | h:768 (c-rows h=0)
  _Float16* B0h = (_Float16*)alloc((size_t)256 * 768 * 2);
  _Float16* B1  = (_Float16*)alloc((size_t)768 * 1536 * 2);  // h0:768 | h1:768 (c-rows h1=0)
  _Float16* B1h = (_Float16*)alloc((size_t)256 * 768 * 2);
  _Float16* Bo  = (_Float16*)alloc((size_t)128 * 256 * 2);   // single-term
  float* b0c  = (float*)alloc(768 * 4);
  float* b1c  = (float*)alloc(768 * 4);
  // aggregation outputs: fp16 hi/lo pairs
  _Float16* XAGG  = (_Float16*)alloc((size_t)T_STEPS * NN * 256 * 2);  // [hi128|lo128] per t
  _Float16* H0AGG = (_Float16*)alloc((size_t)NN * 512 * 2);            // [hi256|lo256]
  _Float16* H1AGG = (_Float16*)alloc((size_t)NN * 512 * 2);
  _Float16* RHAGG = (_Float16*)alloc((size_t)NN * 512 * 2);
  _Float16* h1f   = (_Float16*)alloc((size_t)NN * 256 * 2);  // outproj A
  float* rhf  = (float*)alloc((size_t)NN * 256 * 4);
  float* xw   = (float*)alloc((size_t)NN * 768 * 4);

  // fp32 GRU states live directly in d_out tail
  float* h0c = out + (size_t)T_STEPS * NN * FOUT;
  float* h1c = h0c + (size_t)NN * HD;

  // CSR
  hipMemsetAsync(counts, 0, NN * sizeof(int), stream);
  count_kernel<<<(NE + 255) / 256, 256, 0, stream>>>(dst, counts);
  scan_kernel<<<1, 1024, 0, stream>>>(counts, offs, cursor);
  fill_kernel<<<(NE + 255) / 256, 256, 0, stream>>>(src, dst, cursor, esrc);

  // weight prep. c-gate rows keep all-zero h-part (c h-term via B0h/B1h GEMM).
  hipMemsetAsync(B0, 0, (size_t)768 * 1152 * 2, stream);
  hipMemsetAsync(B1, 0, (size_t)768 * 1536 * 2, stream);
  // B0 x-part: A cols [0,128)=xhi,[128,256)=xlo,[256,384)=xhi -> B: hi@0, hi@128, lo@256
  for (int g = 0; g < 3; ++g) {
    const float* W = Wx0 + (size_t)g * 128 * 256;
    _Float16* D = B0 + (size_t)g * 256 * 1152;
    wtrans<<<dim3(1, 256), 256, 0, stream>>>(W, D, 128, 256, 1152, 0, 0);
    wtrans<<<dim3(1, 256), 256, 0, stream>>>(W, D, 128, 256, 1152, 128, 0);
    wtrans<<<dim3(1, 256), 256, 0, stream>>>(W, D, 128, 256, 1152, 256, 1);
  }
  // B0 h-part: A cols [384,640)=hhi,[640,896)=hlo,[896,1152)=hhi -> hi@384, hi@640, lo@896
  for (int g = 0; g < 2; ++g) {
    const float* W = Wh0 + (size_t)g * 256 * 256;
    _Float16* D = B0 + (size_t)g * 256 * 1152;
    wtrans<<<dim3(1, 256), 256, 0, stream>>>(W, D, 256, 256, 1152, 384, 0);
    wtrans<<<dim3(1, 256), 256, 0, stream>>>(W, D, 256, 256, 1152, 640, 0);
    wtrans<<<dim3(1, 256), 256, 0, stream>>>(W, D, 256, 256, 1152, 896, 1);
  }
  {
    const float* W = Wh0 + (size_t)2 * 256 * 256;
    wtrans<<<dim3(1, 256), 256, 0, stream>>>(W, B0h, 256, 256, 768, 0, 0);
    wtrans<<<dim3(1, 256), 256, 0, stream>>>(W, B0h, 256, 256, 768, 256, 0);
    wtrans<<<dim3(1, 256), 256, 0, stream>>>(W, B0h, 256, 256, 768, 512, 1);
  }
  // B1 h0-part @0 (768), h1-part @768 (768)
  for (int g = 0; g < 3; ++g) {
    const float* W = Wx1 + (size_t)g * 256 * 256;
    _Float16* D = B1 + (size_t)g * 256 * 1536;
    wtrans<<<dim3(1, 256), 256, 0, stream>>>(W, D, 256, 256, 1536, 0, 0);
    wtrans<<<dim3(1, 256), 256, 0, stream>>>(W, D, 256, 256, 1536, 256, 0);
    wtrans<<<dim3(1, 256), 256, 0, stream>>>(W, D, 256, 256, 1536, 512, 1);
  }
  for (int g = 0; g < 2; ++g) {
    const float* W = Wh1 + (size_t)g * 256 * 256;
    _Float16* D = B1 + (size_t)g * 256 * 1536;
    wtrans<<<dim3(1, 256), 256, 0, stream>>>(W, D, 256, 256, 1536, 768, 0);
    wtrans<<<dim3(1, 256), 256, 0, stream>>>(W, D, 256, 256, 1536, 1024, 0);
    wtrans<<<dim3(1, 256), 256, 0, stream>>>(W, D, 256, 256, 1536, 1280, 1);
  }
  {
    const float* W = Wh1 + (size_t)2 * 256 * 256;
    wtrans<<<dim3(1, 256), 256, 0, stream>>>(W, B1h, 256, 256, 768, 0, 0);
    wtrans<<<dim3(1, 256), 256, 0, stream>>>(W, B1h, 256, 256, 768, 256, 0);
    wtrans<<<dim3(1, 256), 256, 0, stream>>>(W, B1h, 256, 256, 768, 512, 1);
  }
  wtrans<<<dim3(1, 128), 256, 0, stream>>>(Wo, Bo, 256, 128, 256, 0, 0);
  bias_comb<<<3, 256, 0, stream>>>(bx0, bh0, b0c);
  bias_comb<<<3, 256, 0, stream>>>(bx1, bh1, b1c);

  // init fp32 h states in out tail
  copy_kernel<<<(2 * NN * HD / 4 + 255) / 256, 256, 0, stream>>>(h0, h0c, 2 * NN * HD / 4);

  dim3 blk(256);
  const int RPG = 20;  // ceil(157 row-tiles / 8 XCDs)
  int g6 = 8 * RPG * 6, g2 = 8 * RPG * 2, g1 = 8 * RPG * 1;
  int agg_grid = NN / 4;

  // all-t x aggregation batched; prime H0AGG = agg(h0_init)
  agg_split_x<<<dim3(agg_grid, T_STEPS), blk, 0, stream>>>(x, offs, esrc, XAGG);
  agg_split<HD><<<agg_grid, blk, 0, stream>>>(h0c, offs, esrc, H0AGG, 512);

  for (int t = 0; t < T_STEPS; ++t) {
    // H1AGG = agg(h1_{t-1})
    agg_split<HD><<<agg_grid, blk, 0, stream>>>(h1c, offs, esrc, H1AGG, 512);

    // ---- layer 0 ----  A = [XAGG 3-term (384) | H0AGG 3-term (768)], K=1152, fused r/u
    gemm_f16<<<g6, blk, 0, stream>>>(XAGG + (size_t)t * NN * 256, 256, 256, 384,
                                     H0AGG, 512, 512, B0, 1152, xw, 768, b0c,
                                     NN, 1152, 1, h0c, nullptr, rhf, 6, RPG);
    agg_split<HD><<<agg_grid, blk, 0, stream>>>(rhf, offs, esrc, RHAGG, 512);
    // c-GEMM K=768 3-term, fused c + state update -> h0c
    gemm_f16<<<g2, blk, 0, stream>>>(RHAGG, 512, 512, 768, nullptr, 0, 0,
                                     B0h, 768, xw, 768, nullptr,
                                     NN, 768, 2, h0c, nullptr, nullptr, 2, RPG);
    agg_split<HD><<<agg_grid, blk, 0, stream>>>(h0c, offs, esrc, H0AGG, 512);  // agg(h0_t)

    // ---- layer 1 ----  A = [H0AGG (768) | H1AGG (768)], K=1536, fused r/u
    gemm_f16<<<g6, blk, 0, stream>>>(H0AGG, 512, 512, 768, H1AGG, 512, 512,
                                     B1, 1536, xw, 768, b1c,
                                     NN, 1536, 1, h1c, nullptr, rhf, 6, RPG);
    agg_split<HD><<<agg_grid, blk, 0, stream>>>(rhf, offs, esrc, RHAGG, 512);
    gemm_f16<<<g2, blk, 0, stream>>>(RHAGG, 512, 512, 768, nullptr, 0, 0,
                                     B1h, 768, xw, 768, nullptr,
                                     NN, 768, 2, h1c, h1f, nullptr, 2, RPG);

    // ---- output projection ----  A = h1f (fp16 mirror), K=256 single-term
    gemm_f16<<<g1, blk, 0, stream>>>(h1f, 256, 256, 256, nullptr, 0, 0,
                                     Bo, 256, out + (size_t)t * NN * FOUT, FOUT, bo,
                                     NN, 256, 0, nullptr, nullptr, nullptr, 1, RPG);
  }
}